// Round 7
// baseline (481.526 us; speedup 1.0000x reference)
//
#include <hip/hip_runtime.h>
#include <cstdint>
#include <cstddef>

#define D_MODEL 1024
#define NH      16
#define HD      64
#define B_SZ    32
#define SEQ     1500
#define MROWS   (B_SZ * SEQ)   // 48000
#define KD      1024
#define NCHUNK  4
#define CLEN    (SEQ / NCHUNK) // 375

typedef __attribute__((ext_vector_type(8))) short bf16x8;
typedef __attribute__((ext_vector_type(4))) float f32x4;
typedef unsigned short u16;

__device__ __forceinline__ u16 f2b(float f) {
  unsigned int x = __float_as_uint(f);
  x = (x + 0x7FFFu + ((x >> 16) & 1u)) >> 16;   // RNE
  return (u16)x;
}

__device__ __forceinline__ unsigned cvtpk(float lo, float hi) {
  unsigned r;
  asm("v_cvt_pk_bf16_f32 %0, %1, %2" : "=v"(r) : "v"(lo), "v"(hi));
  return r;  // lo16 = bf16(lo), hi16 = bf16(hi)
}

#define SCHED_FENCE() asm volatile("" ::: "memory")

// ---------------- prep: cast Wk,Wv -> bf16 (blocks <256) + q-projection (blocks >=256) ----------------
#define WCAST_BLOCKS 256
#define QPROJ_BLOCKS 64

__global__ __launch_bounds__(256) void prep_kernel(const float* __restrict__ Wk,
                                                   const float* __restrict__ Wv,
                                                   const float* __restrict__ hs,
                                                   const float* __restrict__ Wq,
                                                   const float* __restrict__ bq,
                                                   u16* __restrict__ wkvb,
                                                   float* __restrict__ qs) {
  const int tid = threadIdx.x;
  if (blockIdx.x < WCAST_BLOCKS) {
    const int NW = KD * KD / 8;      // 131,072 8-elem items per weight
    int stride = WCAST_BLOCKS * 256;
    for (int i = blockIdx.x * 256 + tid; i < 2 * NW; i += stride) {
      const float* s = (i < NW) ? (Wk + (size_t)i * 8) : (Wv + (size_t)(i - NW) * 8);
      u16* d = wkvb + (size_t)i * 8;
      const float4* s4 = reinterpret_cast<const float4*>(s);
      float4 a = s4[0], b = s4[1];
      u16 u[8];
      u[0]=f2b(a.x); u[1]=f2b(a.y); u[2]=f2b(a.z); u[3]=f2b(a.w);
      u[4]=f2b(b.x); u[5]=f2b(b.y); u[6]=f2b(b.z); u[7]=f2b(b.w);
      *reinterpret_cast<uint4*>(d) = *reinterpret_cast<const uint4*>(u);
    }
  } else {
    // q-proj: 64 blocks; block qb covers Wq rows [qb*16, qb*16+16) for all 32 batches.
    const int qb = blockIdx.x - WCAST_BLOCKS;
    const int n  = qb * 16 + (tid & 15);
    const int bb = tid >> 4;                 // batches bb and bb+16
    const float4* wp  = (const float4*)(Wq + (size_t)n * D_MODEL);
    const float4* x0p = (const float4*)(hs + (size_t)bb * D_MODEL);
    const float4* x1p = (const float4*)(hs + (size_t)(bb + 16) * D_MODEL);
    float a0 = 0.f, a1 = 0.f;
    #pragma unroll 8
    for (int i = 0; i < D_MODEL / 4; ++i) {
      float4 w = wp[i], x0 = x0p[i], x1 = x1p[i];
      a0 += w.x * x0.x + w.y * x0.y + w.z * x0.z + w.w * x0.w;
      a1 += w.x * x1.x + w.y * x1.y + w.z * x1.z + w.w * x1.w;
    }
    const float bqn = bq[n];
    qs[(size_t)bb * D_MODEL + n]        = (a0 + bqn) * 0.125f;   // SCALE^2 folded
    qs[(size_t)(bb + 16) * D_MODEL + n] = (a1 + bqn) * 0.125f;
  }
}

// ================= 128x256 bf16 MFMA GEMM, fp32 A read direct =================
// C[m,n] = sum_k A[m,k]*Bmat[n,k]; A = enc fp32 [48000][1024] (cast to bf16 in-register),
// Bmat [2048][1024] bf16. nt<4 -> Kout (no bias), nt>=4 -> Vout (+bv).
// LDS rows 64 B, 16B-chunk swizzle cp ^= (r>>1)&3 (pre-swizzled global source).
#define GBM 128
#define GBN 256
#define GBK 32
#define GNT (KD / GBK)   // 32 K-tiles

// A-loads: thread t covers row r=t>>2, 32B at (pre-swizzled) chunk pair
__device__ __forceinline__ void loadA(const float* __restrict__ Ag, long m0, int kt,
                                      int tid, float4& x0, float4& x1) {
  int r = tid >> 2, cp = tid & 3;
  int scp = cp ^ ((r >> 1) & 3);
  const float* src = Ag + (m0 + r) * (long)KD + kt * GBK + scp * 8;
  x0 = *reinterpret_cast<const float4*>(src);
  x1 = *reinterpret_cast<const float4*>(src + 4);
}

__device__ __forceinline__ void writeA(u16* lbuf, int tid, float4 x0, float4 x1) {
  uint4 p;
  p.x = cvtpk(x0.x, x0.y);
  p.y = cvtpk(x0.z, x0.w);
  p.z = cvtpk(x1.x, x1.y);
  p.w = cvtpk(x1.z, x1.w);
  *reinterpret_cast<uint4*>(lbuf + (size_t)tid * 8) = p;   // ds_write_b128, linear dest
}

__device__ __forceinline__ void stageB(const u16* __restrict__ Bg, u16* lbuf,
                                       int n0, int kt, int tid) {
  #pragma unroll
  for (int L = 0; L < 2; ++L) {
    int c = tid + L * 512;
    int r = c >> 2, cp = c & 3;
    int scp = cp ^ ((r >> 1) & 3);
    const u16* src = Bg + (size_t)(n0 + r) * KD + kt * GBK + scp * 8;
    __builtin_amdgcn_global_load_lds((const __attribute__((address_space(1))) void*)src,
        (__attribute__((address_space(3))) void*)(lbuf + (size_t)c * 8), 16, 0, 0);
  }
}

__device__ __forceinline__ bf16x8 ldFrag(const u16* buf, int row, int lane) {
  int r  = row + (lane & 15);
  int ch = (lane >> 4) ^ ((r >> 1) & 3);
  return *(const bf16x8*)(buf + (size_t)r * GBK + ch * 8);
}

__global__ __launch_bounds__(512, 4) void gemm_kv(const float* __restrict__ A,
                                                  const u16* __restrict__ Bm,
                                                  const float* __restrict__ bv,
                                                  float* __restrict__ Kout,
                                                  float* __restrict__ Vout) {
  __shared__ __align__(16) char smem[2 * (GBM + GBN) * GBK * 2];   // 48 KiB
  u16* sA0 = (u16*)smem;
  u16* sA1 = sA0 + GBM * GBK;
  u16* sB0 = sA1 + GBM * GBK;
  u16* sB1 = sB0 + GBN * GBK;

  const int tid  = threadIdx.x;
  const int lane = tid & 63;
  const int wid  = tid >> 6;
  const int wr   = wid >> 2;
  const int wc   = wid & 3;

  int bx = (blockIdx.x & 7) * (gridDim.x >> 3) + (blockIdx.x >> 3);
  const int  mt = bx >> 3;
  const int  nt = bx & 7;
  const long m0 = (long)mt * GBM;
  const int  n0 = nt * GBN;

  // --- prologue: issue order A0,A1,B0,A2,B1 (matches steady-state counting)
  float4 p00, p01, p10, p11, aw0, aw1, al0, al1;
  loadA(A, m0, 0, tid, p00, p01);
  loadA(A, m0, 1, tid, p10, p11);
  SCHED_FENCE();
  stageB(Bm, sB0, n0, 0, tid);
  SCHED_FENCE();
  loadA(A, m0, 2, tid, aw0, aw1);
  SCHED_FENCE();
  stageB(Bm, sB1, n0, 1, tid);
  SCHED_FENCE();
  writeA(sA0, tid, p00, p01);    // compiler auto-vmcnt gates the reg use
  writeA(sA1, tid, p10, p11);
  asm volatile("s_waitcnt lgkmcnt(0)" ::: "memory");

  f32x4 acc[4][4] = {};

  for (int t = 0; t < GNT; ++t) {
    // gate: B(t) LDS-resident (manual count; A-reg waits are compiler-exact)
    if (t <= GNT - 3)      { asm volatile("s_waitcnt vmcnt(4)" ::: "memory"); }
    else if (t == GNT - 2) { asm volatile("s_waitcnt vmcnt(2)" ::: "memory"); }
    else                   { asm volatile("s_waitcnt vmcnt(0)" ::: "memory"); }
    __builtin_amdgcn_s_barrier();

    const u16* cA = (t & 1) ? sA1 : sA0;
    const u16* cB = (t & 1) ? sB1 : sB0;
    bf16x8 af[4], bfr[4];
    #pragma unroll
    for (int mf = 0; mf < 4; ++mf) af[mf]  = ldFrag(cA, wr * 64 + mf * 16, lane);
    #pragma unroll
    for (int nf = 0; nf < 4; ++nf) bfr[nf] = ldFrag(cB, wc * 64 + nf * 16, lane);

    // issue A-loads for tile t+3 (hidden under MFMA + next-tile latency)
    if (t + 3 < GNT) loadA(A, m0, t + 3, tid, al0, al1);

    asm volatile("s_waitcnt lgkmcnt(0)" ::: "memory");
    __builtin_amdgcn_s_barrier();

    // stage tile t+2 into the just-consumed buffer
    if (t + 2 < GNT) {
      u16* pA = (t & 1) ? sA1 : sA0;
      u16* pB = (t & 1) ? sB1 : sB0;
      writeA(pA, tid, aw0, aw1);
      stageB(Bm, pB, n0, t + 2, tid);
    }
    aw0 = al0; aw1 = al1;

    #pragma unroll
    for (int mf = 0; mf < 4; ++mf)
      #pragma unroll
      for (int nf = 0; nf < 4; ++nf)
        acc[mf][nf] = __builtin_amdgcn_mfma_f32_16x16x32_bf16(af[mf], bfr[nf], acc[mf][nf], 0, 0, 0);
  }

  // ---- coalesced epilogue via LDS transpose ([32][260] f32 slabs) ----
  __syncthreads();
  float (*ep)[260] = (float(*)[260])smem;

  const bool isV = (nt >= 4);
  float* Co = isV ? Vout : Kout;
  const int ncol0 = isV ? (n0 - 1024) : n0;
  float4 bias4[4];
  #pragma unroll
  for (int k = 0; k < 4; ++k) {
    int c4 = (tid + 512 * k) & 63;
    bias4[k] = isV ? reinterpret_cast<const float4*>(bv)[(ncol0 >> 2) + c4]
                   : make_float4(0.f, 0.f, 0.f, 0.f);
  }

  #pragma unroll
  for (int p = 0; p < 4; ++p) {
    if (wr == (p >> 1)) {
      const int mfb = (p & 1) * 2;
      #pragma unroll
      for (int mm = 0; mm < 2; ++mm)
        #pragma unroll
        for (int nf = 0; nf < 4; ++nf)
          #pragma unroll
          for (int r = 0; r < 4; ++r)
            ep[mm * 16 + (lane >> 4) * 4 + r][wc * 64 + nf * 16 + (lane & 15)] =
                acc[mfb + mm][nf][r];
    }
    __syncthreads();
    #pragma unroll
    for (int k = 0; k < 4; ++k) {
      int idx = tid + 512 * k;
      int row = idx >> 6;
      int c4  = idx & 63;
      long grow = m0 + p * 32 + row;
      float4 v = *reinterpret_cast<const float4*>(&ep[row][c4 * 4]);
      v.x += bias4[k].x; v.y += bias4[k].y; v.z += bias4[k].z; v.w += bias4[k].w;
      *reinterpret_cast<float4*>(&Co[grow * D_MODEL + ncol0 + c4 * 4]) = v;
    }
    __syncthreads();
  }
}

// ---------------- attention pass 1: per-(b,h,chunk) partial online softmax + PV ----------------
__global__ __launch_bounds__(256) void attn_part(const float* __restrict__ qs,
                                                 const float* __restrict__ K,
                                                 const float* __restrict__ V,
                                                 float* __restrict__ part) {
  const int blk = blockIdx.x;          // bh*4 + c
  const int bh = blk >> 2, c = blk & 3;
  const int b = bh >> 4, h = bh & 15;
  const int tid = threadIdx.x;
  const int s0 = c * CLEN;

  __shared__ float sc[CLEN];
  __shared__ float red[256];
  __shared__ float pvs[16][HD];

  // scores: 16 lanes per row, shfl_xor dot-reduce
  const int j  = tid & 15;
  const int rg = tid >> 4;
  const float4 q4 = *(const float4*)(qs + (size_t)b * D_MODEL + h * HD + j * 4);
  float lmax = -1e30f;
  for (int i = rg; i < CLEN; i += 16) {
    const float4 k4 = *(const float4*)(K + (size_t)(b * SEQ + s0 + i) * D_MODEL + h * HD + j * 4);
    float p = q4.x * k4.x + q4.y * k4.y + q4.z * k4.z + q4.w * k4.w;
    p += __shfl_xor(p, 1);
    p += __shfl_xor(p, 2);
    p += __shfl_xor(p, 4);
    p += __shfl_xor(p, 8);
    if (j == 0) sc[i] = p;
    lmax = fmaxf(lmax, p);
  }
  red[tid] = lmax; __syncthreads();
  for (int off = 128; off; off >>= 1) {
    if (tid < off) red[tid] = fmaxf(red[tid], red[tid + off]);
    __syncthreads();
  }
  const float m = red[0]; __syncthreads();

  float lsum = 0.f;
  for (int i = tid; i < CLEN; i += 256) {
    float p = __expf(sc[i] - m);
    sc[i] = p;
    lsum += p;
  }
  red[tid] = lsum; __syncthreads();
  for (int off = 128; off; off >>= 1) {
    if (tid < off) red[tid] += red[tid + off];
    __syncthreads();
  }
  const float l = red[0];

  // partial PV: 16 d-quads x 16 s-groups, float4 per lane
  const int dq = tid & 15;
  const int sg = tid >> 4;
  float4 a4 = make_float4(0.f, 0.f, 0.f, 0.f);
  for (int i = sg; i < CLEN; i += 16) {
    float p = sc[i];
    float4 v4 = *(const float4*)(V + (size_t)(b * SEQ + s0 + i) * D_MODEL + h * HD + dq * 4);
    a4.x += p * v4.x; a4.y += p * v4.y; a4.z += p * v4.z; a4.w += p * v4.w;
  }
  *(float4*)&pvs[sg][dq * 4] = a4;
  __syncthreads();

  if (tid < HD) {
    float a = 0.f;
    #pragma unroll
    for (int g = 0; g < 16; ++g) a += pvs[g][tid];
    float* pp = part + (size_t)blk * 66;
    pp[2 + tid] = a;
    if (tid == 0) { pp[0] = m; pp[1] = l; }
  }
}

// ---------------- o-projection with fused chunk-combine: 8 blocks per batch ----------------
__global__ __launch_bounds__(256) void oproj_comb(const float* __restrict__ part,
                                                  const float* __restrict__ Wo,
                                                  const float* __restrict__ bo,
                                                  float* __restrict__ out) {
  const int b = blockIdx.x >> 3, ch = blockIdx.x & 7;
  const int tid = threadIdx.x;
  __shared__ float xs[D_MODEL];

  { // combine 4 chunks: thread handles head h = tid>>4, dims d..d+3
    const int h = tid >> 4;
    const int d = (tid & 15) * 4;
    const float* pp = part + (size_t)(b * NH + h) * 4 * 66;
    const float m0 = pp[0], l0 = pp[1], m1 = pp[66], l1 = pp[67],
                m2 = pp[132], l2 = pp[133], m3 = pp[198], l3 = pp[199];
    const float M = fmaxf(fmaxf(m0, m1), fmaxf(m2, m3));
    const float w0 = __expf(m0 - M), w1 = __expf(m1 - M),
                w2 = __expf(m2 - M), w3 = __expf(m3 - M);
    const float inv = 1.0f / (l0 * w0 + l1 * w1 + l2 * w2 + l3 * w3);
    #pragma unroll
    for (int jj = 0; jj < 4; ++jj) {
      float o = pp[2 + d + jj] * w0 + pp[68 + d + jj] * w1 +
                pp[134 + d + jj] * w2 + pp[200 + d + jj] * w3;
      xs[h * HD + d + jj] = o * inv;
    }
  }
  __syncthreads();

  const int n = ch * 128 + (tid >> 1);
  const int half = tid & 1;
  const float4* wp = (const float4*)(Wo + (size_t)n * D_MODEL + half * 512);
  const float4* xp = (const float4*)xs + half * 128;
  float a = 0.f;
  #pragma unroll 8
  for (int i = 0; i < 128; ++i) {
    float4 w = wp[i], xv = xp[i];
    a += w.x * xv.x + w.y * xv.y + w.z * xv.z + w.w * xv.w;
  }
  a += __shfl_xor(a, 1);
  if (!half) out[(size_t)b * D_MODEL + n] = a + bo[n];
}

// ---------------- launch ----------------
extern "C" void kernel_launch(void* const* d_in, const int* in_sizes, int n_in,
                              void* d_out, int out_size, void* d_ws, size_t ws_size,
                              hipStream_t stream) {
  const float* hs  = (const float*)d_in[0];
  const float* enc = (const float*)d_in[1];
  const float* Wq  = (const float*)d_in[2];
  const float* bq  = (const float*)d_in[3];
  const float* Wk  = (const float*)d_in[4];
  const float* Wv  = (const float*)d_in[5];
  const float* bv  = (const float*)d_in[6];
  const float* Wo  = (const float*)d_in[7];
  const float* bo  = (const float*)d_in[8];

  float* out   = (float*)d_out;
  float* attnO = out;
  float* Kout  = out + 32768;
  float* Vout  = Kout + (size_t)MROWS * D_MODEL;

  char* ws = (char*)d_ws;
  u16*   wkvb = (u16*)ws;                          // 4,194,304 B
  float* qs   = (float*)(ws + 4194304);            //   131,072 B
  float* part = (float*)(ws + 4194304 + 131072);   //   540,672 B

  prep_kernel<<<WCAST_BLOCKS + QPROJ_BLOCKS, 256, 0, stream>>>(Wk, Wv, hs, Wq, bq, wkvb, qs);

  gemm_kv<<<(MROWS / GBM) * (2048 / GBN), 512, 0, stream>>>(enc, wkvb, bv, Kout, Vout);

  attn_part<<<B_SZ * NH * NCHUNK, 256, 0, stream>>>(qs, Kout, Vout, part);
  oproj_comb<<<B_SZ * 8, 256, 0, stream>>>(part, Wo, bo, attnO);
}

// Round 8
// 458.417 us; speedup vs baseline: 1.0504x; 1.0504x over previous
//
#include <hip/hip_runtime.h>
#include <cstdint>
#include <cstddef>

#define D_MODEL 1024
#define NH      16
#define HD      64
#define B_SZ    32
#define SEQ     1500
#define MROWS   (B_SZ * SEQ)   // 48000
#define KD      1024
#define NCH     16             // wave-private chunks per (b,h)
#define PSTR    68             // part stride: pv[64], m, l, pad2

typedef __attribute__((ext_vector_type(8))) short bf16x8;
typedef __attribute__((ext_vector_type(4))) float f32x4;
typedef unsigned short u16;

__device__ __forceinline__ u16 f2b(float f) {
  unsigned int x = __float_as_uint(f);
  x = (x + 0x7FFFu + ((x >> 16) & 1u)) >> 16;   // RNE
  return (u16)x;
}

// ---------------- fused cast f32->bf16 (blocks <3072) + q-projection rider ----------------
#define CAST_BLOCKS 3072
#define QPROJ_BLOCKS 64   // n-split: each block does 16 Wq rows for all 32 batches

__global__ __launch_bounds__(256) void cast_all_q(const float* __restrict__ enc,
                                                  const float* __restrict__ Wk,
                                                  const float* __restrict__ Wv,
                                                  const float* __restrict__ hs,
                                                  const float* __restrict__ Wq,
                                                  const float* __restrict__ bq,
                                                  u16* __restrict__ encb,
                                                  u16* __restrict__ wkvb,
                                                  float* __restrict__ qs) {
  const int tid = threadIdx.x;
  if (blockIdx.x < CAST_BLOCKS) {
    const int NA = MROWS * KD / 8;   // 6,144,000
    const int NW = KD * KD / 8;      // 131,072
    int stride = CAST_BLOCKS * 256;
    for (int i = blockIdx.x * 256 + tid; i < NA + 2 * NW; i += stride) {
      const float* s; u16* d;
      if (i < NA)            { s = enc + (size_t)i * 8;            d = encb + (size_t)i * 8; }
      else if (i < NA + NW)  { size_t j = i - NA;      s = Wk + j * 8; d = wkvb + j * 8; }
      else                   { size_t j = i - NA - NW; s = Wv + j * 8; d = wkvb + (size_t)NW * 8 + j * 8; }
      const float4* s4 = reinterpret_cast<const float4*>(s);
      float4 a = s4[0], b = s4[1];
      u16 u[8];
      u[0]=f2b(a.x); u[1]=f2b(a.y); u[2]=f2b(a.z); u[3]=f2b(a.w);
      u[4]=f2b(b.x); u[5]=f2b(b.y); u[6]=f2b(b.z); u[7]=f2b(b.w);
      *reinterpret_cast<uint4*>(d) = *reinterpret_cast<const uint4*>(u);
    }
  } else {
    // q-proj rider: 64 blocks, block qb covers Wq rows [qb*16, qb*16+16) for all 32 b.
    const int qb = blockIdx.x - CAST_BLOCKS;
    const int n  = qb * 16 + (tid & 15);
    const int bb = tid >> 4;                 // batches bb and bb+16
    const float4* wp  = (const float4*)(Wq + (size_t)n * D_MODEL);
    const float4* x0p = (const float4*)(hs + (size_t)bb * D_MODEL);
    const float4* x1p = (const float4*)(hs + (size_t)(bb + 16) * D_MODEL);
    float a0 = 0.f, a1 = 0.f;
    #pragma unroll 8
    for (int i = 0; i < D_MODEL / 4; ++i) {
      float4 w = wp[i], x0 = x0p[i], x1 = x1p[i];
      a0 += w.x * x0.x + w.y * x0.y + w.z * x0.z + w.w * x0.w;
      a1 += w.x * x1.x + w.y * x1.y + w.z * x1.z + w.w * x1.w;
    }
    const float bqn = bq[n];
    qs[(size_t)bb * D_MODEL + n]        = (a0 + bqn) * 0.125f;   // SCALE^2 folded
    qs[(size_t)(bb + 16) * D_MODEL + n] = (a1 + bqn) * 0.125f;
  }
}

// ================= 128x256 bf16 MFMA GEMM (round-3/6 proven version, untouched) =================
#define GBM 128
#define GBN 256
#define GBK 32
#define GNT (KD / GBK)   // 32 K-tiles

__device__ __forceinline__ void stageA(const u16* __restrict__ Ag, u16* lbuf,
                                       long m0, int kt, int tid) {
  int c = tid;
  int r = c >> 2, cp = c & 3;
  int scp = cp ^ ((r >> 1) & 3);
  const u16* src = Ag + (m0 + r) * (long)KD + kt * GBK + scp * 8;
  __builtin_amdgcn_global_load_lds((const __attribute__((address_space(1))) void*)src,
      (__attribute__((address_space(3))) void*)(lbuf + (size_t)c * 8), 16, 0, 0);
}

__device__ __forceinline__ void stageB(const u16* __restrict__ Bg, u16* lbuf,
                                       int n0, int kt, int tid) {
  #pragma unroll
  for (int L = 0; L < 2; ++L) {
    int c = tid + L * 512;
    int r = c >> 2, cp = c & 3;
    int scp = cp ^ ((r >> 1) & 3);
    const u16* src = Bg + (size_t)(n0 + r) * KD + kt * GBK + scp * 8;
    __builtin_amdgcn_global_load_lds((const __attribute__((address_space(1))) void*)src,
        (__attribute__((address_space(3))) void*)(lbuf + (size_t)c * 8), 16, 0, 0);
  }
}

__device__ __forceinline__ bf16x8 ldFrag(const u16* buf, int row, int lane) {
  int r  = row + (lane & 15);
  int ch = (lane >> 4) ^ ((r >> 1) & 3);
  return *(const bf16x8*)(buf + (size_t)r * GBK + ch * 8);
}

__global__ __launch_bounds__(512, 4) void gemm_kv(const u16* __restrict__ A,
                                                  const u16* __restrict__ Bm,
                                                  const float* __restrict__ bv,
                                                  float* __restrict__ Kout,
                                                  float* __restrict__ Vout) {
  __shared__ __align__(16) char smem[2 * (GBM + GBN) * GBK * 2];   // 48 KiB
  u16* sA0 = (u16*)smem;
  u16* sA1 = sA0 + GBM * GBK;
  u16* sB0 = sA1 + GBM * GBK;
  u16* sB1 = sB0 + GBN * GBK;

  const int tid  = threadIdx.x;
  const int lane = tid & 63;
  const int wid  = tid >> 6;
  const int wr   = wid >> 2;
  const int wc   = wid & 3;

  int bx = (blockIdx.x & 7) * (gridDim.x >> 3) + (blockIdx.x >> 3);
  const int  mt = bx >> 3;
  const int  nt = bx & 7;
  const long m0 = (long)mt * GBM;
  const int  n0 = nt * GBN;

  stageA(A, sA0, m0, 0, tid);
  stageB(Bm, sB0, n0, 0, tid);
  stageA(A, sA1, m0, 1, tid);
  stageB(Bm, sB1, n0, 1, tid);

  f32x4 acc[4][4] = {};

  for (int t = 0; t < GNT; ++t) {
    if (t == GNT - 1) { asm volatile("s_waitcnt vmcnt(0)" ::: "memory"); }
    else              { asm volatile("s_waitcnt vmcnt(3)" ::: "memory"); }
    __builtin_amdgcn_s_barrier();

    const u16* cA = (t & 1) ? sA1 : sA0;
    const u16* cB = (t & 1) ? sB1 : sB0;
    bf16x8 af[4], bfr[4];
    #pragma unroll
    for (int mf = 0; mf < 4; ++mf) af[mf]  = ldFrag(cA, wr * 64 + mf * 16, lane);
    #pragma unroll
    for (int nf = 0; nf < 4; ++nf) bfr[nf] = ldFrag(cB, wc * 64 + nf * 16, lane);
    asm volatile("s_waitcnt lgkmcnt(0)" ::: "memory");
    __builtin_amdgcn_s_barrier();

    if (t + 2 < GNT) {
      u16* pA = (t & 1) ? sA1 : sA0;
      u16* pB = (t & 1) ? sB1 : sB0;
      stageA(A, pA, m0, t + 2, tid);
      stageB(Bm, pB, n0, t + 2, tid);
    }

    #pragma unroll
    for (int mf = 0; mf < 4; ++mf)
      #pragma unroll
      for (int nf = 0; nf < 4; ++nf)
        acc[mf][nf] = __builtin_amdgcn_mfma_f32_16x16x32_bf16(af[mf], bfr[nf], acc[mf][nf], 0, 0, 0);
  }

  // ---- coalesced epilogue via LDS transpose ([32][260] f32 slabs) ----
  __syncthreads();
  float (*ep)[260] = (float(*)[260])smem;

  const bool isV = (nt >= 4);
  float* Co = isV ? Vout : Kout;
  const int ncol0 = isV ? (n0 - 1024) : n0;
  float4 bias4[4];
  #pragma unroll
  for (int k = 0; k < 4; ++k) {
    int c4 = (tid + 512 * k) & 63;
    bias4[k] = isV ? reinterpret_cast<const float4*>(bv)[(ncol0 >> 2) + c4]
                   : make_float4(0.f, 0.f, 0.f, 0.f);
  }

  #pragma unroll
  for (int p = 0; p < 4; ++p) {
    if (wr == (p >> 1)) {
      const int mfb = (p & 1) * 2;
      #pragma unroll
      for (int mm = 0; mm < 2; ++mm)
        #pragma unroll
        for (int nf = 0; nf < 4; ++nf)
          #pragma unroll
          for (int r = 0; r < 4; ++r)
            ep[mm * 16 + (lane >> 4) * 4 + r][wc * 64 + nf * 16 + (lane & 15)] =
                acc[mfb + mm][nf][r];
    }
    __syncthreads();
    #pragma unroll
    for (int k = 0; k < 4; ++k) {
      int idx = tid + 512 * k;
      int row = idx >> 6;
      int c4  = idx & 63;
      long grow = m0 + p * 32 + row;
      float4 v = *reinterpret_cast<const float4*>(&ep[row][c4 * 4]);
      v.x += bias4[k].x; v.y += bias4[k].y; v.z += bias4[k].z; v.w += bias4[k].w;
      *reinterpret_cast<float4*>(&Co[grow * D_MODEL + ncol0 + c4 * 4]) = v;
    }
    __syncthreads();
  }
}

// ---------------- attention pass 1: wave-private chunks, zero block barriers ----------------
// grid: bh*4 + qb; each of the 4 waves handles chunk c = qb*4 + w (16 chunks per bh).
// part[bh*16+c] = { pv[64], m, l, pad2 }  (stride PSTR=68, pv 16B-aligned)
__global__ __launch_bounds__(256) void attn_part(const float* __restrict__ qs,
                                                 const float* __restrict__ K,
                                                 const float* __restrict__ V,
                                                 float* __restrict__ part) {
  const int blk = blockIdx.x;
  const int bh = blk >> 2, qb = blk & 3;
  const int b = bh >> 4, h = bh & 15;
  const int w = threadIdx.x >> 6;
  const int lane = threadIdx.x & 63;
  const int c = qb * 4 + w;
  const int s0 = (c * SEQ) >> 4;
  const int L = (((c + 1) * SEQ) >> 4) - s0;   // 93 or 94

  __shared__ float scs[4][96];
  float* sc = scs[w];

  const int j  = lane & 15;            // d-quad
  const int rg = lane >> 4;            // row subgroup 0..3
  const float4 q4 = *(const float4*)(qs + (size_t)b * D_MODEL + h * HD + j * 4);

  // scores: rows i = rg, rg+4, ... (4 consecutive rows in flight per wave-instr)
  float lmax = -1e30f;
  for (int i = rg; i < L; i += 4) {
    const float4 k4 = *(const float4*)(K + (size_t)(b * SEQ + s0 + i) * D_MODEL + h * HD + j * 4);
    float p = q4.x * k4.x + q4.y * k4.y + q4.z * k4.z + q4.w * k4.w;
    p += __shfl_xor(p, 1);
    p += __shfl_xor(p, 2);
    p += __shfl_xor(p, 4);
    p += __shfl_xor(p, 8);
    if (j == 0) sc[i] = p;
    lmax = fmaxf(lmax, p);
  }
  lmax = fmaxf(lmax, __shfl_xor(lmax, 16));
  lmax = fmaxf(lmax, __shfl_xor(lmax, 32));
  const float m = lmax;
  asm volatile("s_waitcnt lgkmcnt(0)" ::: "memory");

  // exp + sum (wave-local, lane-strided)
  float lsum = 0.f;
  for (int i = lane; i < L; i += 64) {
    float p = __expf(sc[i] - m);
    sc[i] = p;
    lsum += p;
  }
  lsum += __shfl_xor(lsum, 1);
  lsum += __shfl_xor(lsum, 2);
  lsum += __shfl_xor(lsum, 4);
  lsum += __shfl_xor(lsum, 8);
  lsum += __shfl_xor(lsum, 16);
  lsum += __shfl_xor(lsum, 32);
  asm volatile("s_waitcnt lgkmcnt(0)" ::: "memory");

  // partial PV: lane j covers dims j*4..j*4+3, rows rg-strided
  float4 a4 = make_float4(0.f, 0.f, 0.f, 0.f);
  for (int i = rg; i < L; i += 4) {
    float p = sc[i];
    float4 v4 = *(const float4*)(V + (size_t)(b * SEQ + s0 + i) * D_MODEL + h * HD + j * 4);
    a4.x += p * v4.x; a4.y += p * v4.y; a4.z += p * v4.z; a4.w += p * v4.w;
  }
  a4.x += __shfl_xor(a4.x, 16); a4.x += __shfl_xor(a4.x, 32);
  a4.y += __shfl_xor(a4.y, 16); a4.y += __shfl_xor(a4.y, 32);
  a4.z += __shfl_xor(a4.z, 16); a4.z += __shfl_xor(a4.z, 32);
  a4.w += __shfl_xor(a4.w, 16); a4.w += __shfl_xor(a4.w, 32);

  float* pp = part + (size_t)(bh * NCH + c) * PSTR;
  if (lane < 16) *(float4*)(pp + lane * 4) = a4;
  if (lane == 0) { pp[64] = m; pp[65] = lsum; }
}

// ---------------- o-projection with fused 16-way chunk-combine: 8 blocks per batch ----------------
__global__ __launch_bounds__(256) void oproj_comb(const float* __restrict__ part,
                                                  const float* __restrict__ Wo,
                                                  const float* __restrict__ bo,
                                                  float* __restrict__ out) {
  const int b = blockIdx.x >> 3, ch = blockIdx.x & 7;
  const int tid = threadIdx.x;
  __shared__ float xs[D_MODEL];

  { // combine 16 chunks: thread handles head h = tid>>4, dims d..d+3
    const int h = tid >> 4;
    const int d = (tid & 15) * 4;
    const float* pp = part + (size_t)(b * NH + h) * NCH * PSTR;
    float M = -1e30f;
    #pragma unroll
    for (int cc = 0; cc < NCH; ++cc) M = fmaxf(M, pp[cc * PSTR + 64]);
    float Lsum = 0.f;
    float4 o = make_float4(0.f, 0.f, 0.f, 0.f);
    #pragma unroll
    for (int cc = 0; cc < NCH; ++cc) {
      const float wgt = __expf(pp[cc * PSTR + 64] - M);
      Lsum += pp[cc * PSTR + 65] * wgt;
      float4 pv = *(const float4*)(pp + cc * PSTR + d);
      o.x += pv.x * wgt; o.y += pv.y * wgt; o.z += pv.z * wgt; o.w += pv.w * wgt;
    }
    const float inv = 1.0f / Lsum;
    xs[h * HD + d]     = o.x * inv;
    xs[h * HD + d + 1] = o.y * inv;
    xs[h * HD + d + 2] = o.z * inv;
    xs[h * HD + d + 3] = o.w * inv;
  }
  __syncthreads();

  const int n = ch * 128 + (tid >> 1);
  const int half = tid & 1;
  const float4* wp = (const float4*)(Wo + (size_t)n * D_MODEL + half * 512);
  const float4* xp = (const float4*)xs + half * 128;
  float a = 0.f;
  #pragma unroll 8
  for (int i = 0; i < 128; ++i) {
    float4 w = wp[i], xv = xp[i];
    a += w.x * xv.x + w.y * xv.y + w.z * xv.z + w.w * xv.w;
  }
  a += __shfl_xor(a, 1);
  if (!half) out[(size_t)b * D_MODEL + n] = a + bo[n];
}

// ---------------- launch ----------------
extern "C" void kernel_launch(void* const* d_in, const int* in_sizes, int n_in,
                              void* d_out, int out_size, void* d_ws, size_t ws_size,
                              hipStream_t stream) {
  const float* hs  = (const float*)d_in[0];
  const float* enc = (const float*)d_in[1];
  const float* Wq  = (const float*)d_in[2];
  const float* bq  = (const float*)d_in[3];
  const float* Wk  = (const float*)d_in[4];
  const float* Wv  = (const float*)d_in[5];
  const float* bv  = (const float*)d_in[6];
  const float* Wo  = (const float*)d_in[7];
  const float* bo  = (const float*)d_in[8];

  float* out   = (float*)d_out;
  float* attnO = out;
  float* Kout  = out + 32768;
  float* Vout  = Kout + (size_t)MROWS * D_MODEL;

  char* ws = (char*)d_ws;
  const size_t off_wkvb = (size_t)MROWS * D_MODEL * 2;        // 98,304,000
  const size_t off_qs   = off_wkvb + 4194304;
  const size_t off_part = off_qs + 131072;                    // 512*16*68*4 = 2,228,224 B

  u16*   encb = (u16*)ws;
  u16*   wkvb = (u16*)(ws + off_wkvb);
  float* qs   = (float*)(ws + off_qs);
  float* part = (float*)(ws + off_part);

  cast_all_q<<<CAST_BLOCKS + QPROJ_BLOCKS, 256, 0, stream>>>(enc, Wk, Wv, hs, Wq, bq,
                                                             encb, wkvb, qs);

  gemm_kv<<<(MROWS / GBM) * (2048 / GBN), 512, 0, stream>>>(encb, wkvb, bv, Kout, Vout);

  attn_part<<<B_SZ * NH * 4, 256, 0, stream>>>(qs, Kout, Vout, part);
  oproj_comb<<<B_SZ * 8, 256, 0, stream>>>(part, Wo, bo, attnO);
}

// Round 9
// 453.621 us; speedup vs baseline: 1.0615x; 1.0106x over previous
//
#include <hip/hip_runtime.h>
#include <cstdint>
#include <cstddef>

#define D_MODEL 1024
#define NH      16
#define HD      64
#define B_SZ    32
#define SEQ     1500
#define MROWS   (B_SZ * SEQ)   // 48000
#define KD      1024
#define NCH     16             // s-chunks per batch
#define PSTR    68             // part stride: pv[64], m, l, pad2

typedef __attribute__((ext_vector_type(8))) short bf16x8;
typedef __attribute__((ext_vector_type(4))) float f32x4;
typedef unsigned short u16;

__device__ __forceinline__ u16 f2b(float f) {
  unsigned int x = __float_as_uint(f);
  x = (x + 0x7FFFu + ((x >> 16) & 1u)) >> 16;   // RNE
  return (u16)x;
}

// ---------------- fused cast f32->bf16 (blocks <3072) + q-projection rider ----------------
#define CAST_BLOCKS 3072
#define QPROJ_BLOCKS 64   // n-split: each block does 16 Wq rows for all 32 batches

__global__ __launch_bounds__(256) void cast_all_q(const float* __restrict__ enc,
                                                  const float* __restrict__ Wk,
                                                  const float* __restrict__ Wv,
                                                  const float* __restrict__ hs,
                                                  const float* __restrict__ Wq,
                                                  const float* __restrict__ bq,
                                                  u16* __restrict__ encb,
                                                  u16* __restrict__ wkvb,
                                                  float* __restrict__ qs) {
  const int tid = threadIdx.x;
  if (blockIdx.x < CAST_BLOCKS) {
    const int NA = MROWS * KD / 8;   // 6,144,000
    const int NW = KD * KD / 8;      // 131,072
    int stride = CAST_BLOCKS * 256;
    for (int i = blockIdx.x * 256 + tid; i < NA + 2 * NW; i += stride) {
      const float* s; u16* d;
      if (i < NA)            { s = enc + (size_t)i * 8;            d = encb + (size_t)i * 8; }
      else if (i < NA + NW)  { size_t j = i - NA;      s = Wk + j * 8; d = wkvb + j * 8; }
      else                   { size_t j = i - NA - NW; s = Wv + j * 8; d = wkvb + (size_t)NW * 8 + j * 8; }
      const float4* s4 = reinterpret_cast<const float4*>(s);
      float4 a = s4[0], b = s4[1];
      u16 u[8];
      u[0]=f2b(a.x); u[1]=f2b(a.y); u[2]=f2b(a.z); u[3]=f2b(a.w);
      u[4]=f2b(b.x); u[5]=f2b(b.y); u[6]=f2b(b.z); u[7]=f2b(b.w);
      *reinterpret_cast<uint4*>(d) = *reinterpret_cast<const uint4*>(u);
    }
  } else {
    // q-proj rider: 64 blocks, block qb covers Wq rows [qb*16, qb*16+16) for all 32 b.
    const int qb = blockIdx.x - CAST_BLOCKS;
    const int n  = qb * 16 + (tid & 15);
    const int bb = tid >> 4;                 // batches bb and bb+16
    const float4* wp  = (const float4*)(Wq + (size_t)n * D_MODEL);
    const float4* x0p = (const float4*)(hs + (size_t)bb * D_MODEL);
    const float4* x1p = (const float4*)(hs + (size_t)(bb + 16) * D_MODEL);
    float a0 = 0.f, a1 = 0.f;
    #pragma unroll 8
    for (int i = 0; i < D_MODEL / 4; ++i) {
      float4 w = wp[i], x0 = x0p[i], x1 = x1p[i];
      a0 += w.x * x0.x + w.y * x0.y + w.z * x0.z + w.w * x0.w;
      a1 += w.x * x1.x + w.y * x1.y + w.z * x1.z + w.w * x1.w;
    }
    const float bqn = bq[n];
    qs[(size_t)bb * D_MODEL + n]        = (a0 + bqn) * 0.125f;   // SCALE^2 folded
    qs[(size_t)(bb + 16) * D_MODEL + n] = (a1 + bqn) * 0.125f;
  }
}

// ================= 128x256 bf16 MFMA GEMM (round-3/6 proven version, untouched) =================
#define GBM 128
#define GBN 256
#define GBK 32
#define GNT (KD / GBK)   // 32 K-tiles

__device__ __forceinline__ void stageA(const u16* __restrict__ Ag, u16* lbuf,
                                       long m0, int kt, int tid) {
  int c = tid;
  int r = c >> 2, cp = c & 3;
  int scp = cp ^ ((r >> 1) & 3);
  const u16* src = Ag + (m0 + r) * (long)KD + kt * GBK + scp * 8;
  __builtin_amdgcn_global_load_lds((const __attribute__((address_space(1))) void*)src,
      (__attribute__((address_space(3))) void*)(lbuf + (size_t)c * 8), 16, 0, 0);
}

__device__ __forceinline__ void stageB(const u16* __restrict__ Bg, u16* lbuf,
                                       int n0, int kt, int tid) {
  #pragma unroll
  for (int L = 0; L < 2; ++L) {
    int c = tid + L * 512;
    int r = c >> 2, cp = c & 3;
    int scp = cp ^ ((r >> 1) & 3);
    const u16* src = Bg + (size_t)(n0 + r) * KD + kt * GBK + scp * 8;
    __builtin_amdgcn_global_load_lds((const __attribute__((address_space(1))) void*)src,
        (__attribute__((address_space(3))) void*)(lbuf + (size_t)c * 8), 16, 0, 0);
  }
}

__device__ __forceinline__ bf16x8 ldFrag(const u16* buf, int row, int lane) {
  int r  = row + (lane & 15);
  int ch = (lane >> 4) ^ ((r >> 1) & 3);
  return *(const bf16x8*)(buf + (size_t)r * GBK + ch * 8);
}

__global__ __launch_bounds__(512, 4) void gemm_kv(const u16* __restrict__ A,
                                                  const u16* __restrict__ Bm,
                                                  const float* __restrict__ bv,
                                                  float* __restrict__ Kout,
                                                  float* __restrict__ Vout) {
  __shared__ __align__(16) char smem[2 * (GBM + GBN) * GBK * 2];   // 48 KiB
  u16* sA0 = (u16*)smem;
  u16* sA1 = sA0 + GBM * GBK;
  u16* sB0 = sA1 + GBM * GBK;
  u16* sB1 = sB0 + GBN * GBK;

  const int tid  = threadIdx.x;
  const int lane = tid & 63;
  const int wid  = tid >> 6;
  const int wr   = wid >> 2;
  const int wc   = wid & 3;

  int bx = (blockIdx.x & 7) * (gridDim.x >> 3) + (blockIdx.x >> 3);
  const int  mt = bx >> 3;
  const int  nt = bx & 7;
  const long m0 = (long)mt * GBM;
  const int  n0 = nt * GBN;

  stageA(A, sA0, m0, 0, tid);
  stageB(Bm, sB0, n0, 0, tid);
  stageA(A, sA1, m0, 1, tid);
  stageB(Bm, sB1, n0, 1, tid);

  f32x4 acc[4][4] = {};

  for (int t = 0; t < GNT; ++t) {
    if (t == GNT - 1) { asm volatile("s_waitcnt vmcnt(0)" ::: "memory"); }
    else              { asm volatile("s_waitcnt vmcnt(3)" ::: "memory"); }
    __builtin_amdgcn_s_barrier();

    const u16* cA = (t & 1) ? sA1 : sA0;
    const u16* cB = (t & 1) ? sB1 : sB0;
    bf16x8 af[4], bfr[4];
    #pragma unroll
    for (int mf = 0; mf < 4; ++mf) af[mf]  = ldFrag(cA, wr * 64 + mf * 16, lane);
    #pragma unroll
    for (int nf = 0; nf < 4; ++nf) bfr[nf] = ldFrag(cB, wc * 64 + nf * 16, lane);
    asm volatile("s_waitcnt lgkmcnt(0)" ::: "memory");
    __builtin_amdgcn_s_barrier();

    if (t + 2 < GNT) {
      u16* pA = (t & 1) ? sA1 : sA0;
      u16* pB = (t & 1) ? sB1 : sB0;
      stageA(A, pA, m0, t + 2, tid);
      stageB(Bm, pB, n0, t + 2, tid);
    }

    #pragma unroll
    for (int mf = 0; mf < 4; ++mf)
      #pragma unroll
      for (int nf = 0; nf < 4; ++nf)
        acc[mf][nf] = __builtin_amdgcn_mfma_f32_16x16x32_bf16(af[mf], bfr[nf], acc[mf][nf], 0, 0, 0);
  }

  // ---- coalesced epilogue via LDS transpose ([32][260] f32 slabs) ----
  __syncthreads();
  float (*ep)[260] = (float(*)[260])smem;

  const bool isV = (nt >= 4);
  float* Co = isV ? Vout : Kout;
  const int ncol0 = isV ? (n0 - 1024) : n0;
  float4 bias4[4];
  #pragma unroll
  for (int k = 0; k < 4; ++k) {
    int c4 = (tid + 512 * k) & 63;
    bias4[k] = isV ? reinterpret_cast<const float4*>(bv)[(ncol0 >> 2) + c4]
                   : make_float4(0.f, 0.f, 0.f, 0.f);
  }

  #pragma unroll
  for (int p = 0; p < 4; ++p) {
    if (wr == (p >> 1)) {
      const int mfb = (p & 1) * 2;
      #pragma unroll
      for (int mm = 0; mm < 2; ++mm)
        #pragma unroll
        for (int nf = 0; nf < 4; ++nf)
          #pragma unroll
          for (int r = 0; r < 4; ++r)
            ep[mm * 16 + (lane >> 4) * 4 + r][wc * 64 + nf * 16 + (lane & 15)] =
                acc[mfb + mm][nf][r];
    }
    __syncthreads();
    #pragma unroll
    for (int k = 0; k < 4; ++k) {
      int idx = tid + 512 * k;
      int row = idx >> 6;
      int c4  = idx & 63;
      long grow = m0 + p * 32 + row;
      float4 v = *reinterpret_cast<const float4*>(&ep[row][c4 * 4]);
      v.x += bias4[k].x; v.y += bias4[k].y; v.z += bias4[k].z; v.w += bias4[k].w;
      *reinterpret_cast<float4*>(&Co[grow * D_MODEL + ncol0 + c4 * 4]) = v;
    }
    __syncthreads();
  }
}

// ---------------- attention pass 1: full-row streaming, all 16 heads per block ----------------
// grid: b*NCH + c. Block reads K[b][s][:] and V[b][s][:] as ((float4*)row)[tid]
// (wave = 1024 contiguous B, block = full 4KB row). head h = tid>>4, d-quad j = tid&15.
// Online softmax in registers; no LDS, no barriers.
// part[(b*NH+h)*NCH+c] = { pv[64], m, l, pad2 }  (stride PSTR=68)
__global__ __launch_bounds__(256) void attn_part(const float* __restrict__ qs,
                                                 const float* __restrict__ K,
                                                 const float* __restrict__ V,
                                                 float* __restrict__ part) {
  const int b = blockIdx.x >> 4;
  const int c = blockIdx.x & 15;
  const int tid = threadIdx.x;
  const int h = tid >> 4;
  const int j = tid & 15;
  const int s0 = (c * SEQ) >> 4;
  const int s1 = (((c + 1) * SEQ) >> 4);

  const float4 q4 = ((const float4*)(qs + (size_t)b * D_MODEL))[tid];  // = q[h*64+j*4..]
  float m = -1e30f, l = 0.f;
  float4 pv = make_float4(0.f, 0.f, 0.f, 0.f);

  int i = s0;
  for (; i + 2 <= s1; i += 2) {
    const float4 kA = ((const float4*)(K + (size_t)(b * SEQ + i) * D_MODEL))[tid];
    const float4 vA = ((const float4*)(V + (size_t)(b * SEQ + i) * D_MODEL))[tid];
    const float4 kB = ((const float4*)(K + (size_t)(b * SEQ + i + 1) * D_MODEL))[tid];
    const float4 vB = ((const float4*)(V + (size_t)(b * SEQ + i + 1) * D_MODEL))[tid];

    float sA = kA.x * q4.x + kA.y * q4.y + kA.z * q4.z + kA.w * q4.w;
    sA += __shfl_xor(sA, 1); sA += __shfl_xor(sA, 2);
    sA += __shfl_xor(sA, 4); sA += __shfl_xor(sA, 8);
    float mn = fmaxf(m, sA);
    float sc = __expf(m - mn);
    float p  = __expf(sA - mn);
    m = mn;
    l = l * sc + p;
    pv.x = pv.x * sc + p * vA.x; pv.y = pv.y * sc + p * vA.y;
    pv.z = pv.z * sc + p * vA.z; pv.w = pv.w * sc + p * vA.w;

    float sB = kB.x * q4.x + kB.y * q4.y + kB.z * q4.z + kB.w * q4.w;
    sB += __shfl_xor(sB, 1); sB += __shfl_xor(sB, 2);
    sB += __shfl_xor(sB, 4); sB += __shfl_xor(sB, 8);
    mn = fmaxf(m, sB);
    sc = __expf(m - mn);
    p  = __expf(sB - mn);
    m = mn;
    l = l * sc + p;
    pv.x = pv.x * sc + p * vB.x; pv.y = pv.y * sc + p * vB.y;
    pv.z = pv.z * sc + p * vB.z; pv.w = pv.w * sc + p * vB.w;
  }
  if (i < s1) {
    const float4 kA = ((const float4*)(K + (size_t)(b * SEQ + i) * D_MODEL))[tid];
    const float4 vA = ((const float4*)(V + (size_t)(b * SEQ + i) * D_MODEL))[tid];
    float sA = kA.x * q4.x + kA.y * q4.y + kA.z * q4.z + kA.w * q4.w;
    sA += __shfl_xor(sA, 1); sA += __shfl_xor(sA, 2);
    sA += __shfl_xor(sA, 4); sA += __shfl_xor(sA, 8);
    float mn = fmaxf(m, sA);
    float sc = __expf(m - mn);
    float p  = __expf(sA - mn);
    m = mn;
    l = l * sc + p;
    pv.x = pv.x * sc + p * vA.x; pv.y = pv.y * sc + p * vA.y;
    pv.z = pv.z * sc + p * vA.z; pv.w = pv.w * sc + p * vA.w;
  }

  float* pp = part + ((size_t)(b * NH + h) * NCH + c) * PSTR;
  *(float4*)(pp + j * 4) = pv;
  if (j == 0) { pp[64] = m; pp[65] = l; }
}

// ---------------- o-projection with fused 16-way chunk-combine: 8 blocks per batch ----------------
__global__ __launch_bounds__(256) void oproj_comb(const float* __restrict__ part,
                                                  const float* __restrict__ Wo,
                                                  const float* __restrict__ bo,
                                                  float* __restrict__ out) {
  const int b = blockIdx.x >> 3, ch = blockIdx.x & 7;
  const int tid = threadIdx.x;
  __shared__ float xs[D_MODEL];

  { // combine 16 chunks: thread handles head h = tid>>4, dims d..d+3
    const int h = tid >> 4;
    const int d = (tid & 15) * 4;
    const float* pp = part + (size_t)(b * NH + h) * NCH * PSTR;
    float M = -1e30f;
    #pragma unroll
    for (int cc = 0; cc < NCH; ++cc) M = fmaxf(M, pp[cc * PSTR + 64]);
    float Lsum = 0.f;
    float4 o = make_float4(0.f, 0.f, 0.f, 0.f);
    #pragma unroll
    for (int cc = 0; cc < NCH; ++cc) {
      const float wgt = __expf(pp[cc * PSTR + 64] - M);
      Lsum += pp[cc * PSTR + 65] * wgt;
      float4 pv = *(const float4*)(pp + cc * PSTR + d);
      o.x += pv.x * wgt; o.y += pv.y * wgt; o.z += pv.z * wgt; o.w += pv.w * wgt;
    }
    const float inv = 1.0f / Lsum;
    xs[h * HD + d]     = o.x * inv;
    xs[h * HD + d + 1] = o.y * inv;
    xs[h * HD + d + 2] = o.z * inv;
    xs[h * HD + d + 3] = o.w * inv;
  }
  __syncthreads();

  const int n = ch * 128 + (tid >> 1);
  const int half = tid & 1;
  const float4* wp = (const float4*)(Wo + (size_t)n * D_MODEL + half * 512);
  const float4* xp = (const float4*)xs + half * 128;
  float a = 0.f;
  #pragma unroll 8
  for (int i = 0; i < 128; ++i) {
    float4 w = wp[i], xv = xp[i];
    a += w.x * xv.x + w.y * xv.y + w.z * xv.z + w.w * xv.w;
  }
  a += __shfl_xor(a, 1);
  if (!half) out[(size_t)b * D_MODEL + n] = a + bo[n];
}

// ---------------- launch ----------------
extern "C" void kernel_launch(void* const* d_in, const int* in_sizes, int n_in,
                              void* d_out, int out_size, void* d_ws, size_t ws_size,
                              hipStream_t stream) {
  const float* hs  = (const float*)d_in[0];
  const float* enc = (const float*)d_in[1];
  const float* Wq  = (const float*)d_in[2];
  const float* bq  = (const float*)d_in[3];
  const float* Wk  = (const float*)d_in[4];
  const float* Wv  = (const float*)d_in[5];
  const float* bv  = (const float*)d_in[6];
  const float* Wo  = (const float*)d_in[7];
  const float* bo  = (const float*)d_in[8];

  float* out   = (float*)d_out;
  float* attnO = out;
  float* Kout  = out + 32768;
  float* Vout  = Kout + (size_t)MROWS * D_MODEL;

  char* ws = (char*)d_ws;
  const size_t off_wkvb = (size_t)MROWS * D_MODEL * 2;        // 98,304,000
  const size_t off_qs   = off_wkvb + 4194304;
  const size_t off_part = off_qs + 131072;                    // 512*16*68*4 = 2,228,224 B

  u16*   encb = (u16*)ws;
  u16*   wkvb = (u16*)(ws + off_wkvb);
  float* qs   = (float*)(ws + off_qs);
  float* part = (float*)(ws + off_part);

  cast_all_q<<<CAST_BLOCKS + QPROJ_BLOCKS, 256, 0, stream>>>(enc, Wk, Wv, hs, Wq, bq,
                                                             encb, wkvb, qs);

  gemm_kv<<<(MROWS / GBM) * (2048 / GBN), 512, 0, stream>>>(encb, wkvb, bv, Kout, Vout);

  attn_part<<<B_SZ * NCH, 256, 0, stream>>>(qs, Kout, Vout, part);
  oproj_comb<<<B_SZ * 8, 256, 0, stream>>>(part, Wo, bo, attnO);
}

// Round 10
// 438.712 us; speedup vs baseline: 1.0976x; 1.0340x over previous
//
#include <hip/hip_runtime.h>
#include <cstdint>
#include <cstddef>

#define D_MODEL 1024
#define NH      16
#define HD      64
#define B_SZ    32
#define SEQ     1500
#define MROWS   (B_SZ * SEQ)   // 48000
#define KD      1024
#define NCH     16             // s-chunks per batch
#define PSTR    68             // part stride: pv[64], m, l, pad2

typedef __attribute__((ext_vector_type(8))) short bf16x8;
typedef __attribute__((ext_vector_type(4))) float f32x4;
typedef unsigned short u16;

__device__ __forceinline__ u16 f2b(float f) {
  unsigned int x = __float_as_uint(f);
  x = (x + 0x7FFFu + ((x >> 16) & 1u)) >> 16;   // RNE
  return (u16)x;
}

// ---------------- cast + q-proj, role-split by block range ----------------
// enc: 3000 blocks x 256 thr x 16 float4 = 12,288,000 float4 (exact cover)
// W:     64 blocks x 256 thr x 32 float4 =    524,288 float4 (Wk then Wv)
// qproj: 64 blocks
#define ENC_BLOCKS 3000
#define W_BLOCKS   64
#define QPROJ_BLOCKS 64

__global__ __launch_bounds__(256) void cast_all_q(const float* __restrict__ enc,
                                                  const float* __restrict__ Wk,
                                                  const float* __restrict__ Wv,
                                                  const float* __restrict__ hs,
                                                  const float* __restrict__ Wq,
                                                  const float* __restrict__ bq,
                                                  u16* __restrict__ encb,
                                                  u16* __restrict__ wkvb,
                                                  float* __restrict__ qs) {
  const int tid = threadIdx.x;
  const int bid = blockIdx.x;
  if (bid < ENC_BLOCKS) {
    const float4* s4 = (const float4*)enc;
    const size_t base = (size_t)bid * 256 + tid;
    #pragma unroll
    for (int k = 0; k < 16; ++k) {
      size_t i = base + (size_t)k * (ENC_BLOCKS * 256);
      float4 a = s4[i];
      u16 u[4] = { f2b(a.x), f2b(a.y), f2b(a.z), f2b(a.w) };
      *reinterpret_cast<uint2*>(encb + i * 4) = *reinterpret_cast<const uint2*>(u);
    }
  } else if (bid < ENC_BLOCKS + W_BLOCKS) {
    const int wb = bid - ENC_BLOCKS;
    const size_t base = (size_t)wb * 256 + tid;
    const int NW4 = KD * KD / 4;           // 262,144 float4 per weight
    #pragma unroll
    for (int k = 0; k < 32; ++k) {
      size_t i = base + (size_t)k * (W_BLOCKS * 256);
      const float4* s4 = (i < (size_t)NW4) ? (const float4*)Wk : (const float4*)Wv;
      size_t j = (i < (size_t)NW4) ? i : i - NW4;
      float4 a = s4[j];
      u16 u[4] = { f2b(a.x), f2b(a.y), f2b(a.z), f2b(a.w) };
      *reinterpret_cast<uint2*>(wkvb + i * 4) = *reinterpret_cast<const uint2*>(u);
    }
  } else {
    // q-proj: block qb covers Wq rows [qb*16, qb*16+16) for all 32 batches
    const int qb = bid - ENC_BLOCKS - W_BLOCKS;
    const int n  = qb * 16 + (tid & 15);
    const int bb = tid >> 4;
    const float4* wp  = (const float4*)(Wq + (size_t)n * D_MODEL);
    const float4* x0p = (const float4*)(hs + (size_t)bb * D_MODEL);
    const float4* x1p = (const float4*)(hs + (size_t)(bb + 16) * D_MODEL);
    float a0 = 0.f, a1 = 0.f;
    #pragma unroll 8
    for (int i = 0; i < D_MODEL / 4; ++i) {
      float4 w = wp[i], x0 = x0p[i], x1 = x1p[i];
      a0 += w.x * x0.x + w.y * x0.y + w.z * x0.z + w.w * x0.w;
      a1 += w.x * x1.x + w.y * x1.y + w.z * x1.z + w.w * x1.w;
    }
    const float bqn = bq[n];
    qs[(size_t)bb * D_MODEL + n]        = (a0 + bqn) * 0.125f;   // SCALE^2 folded
    qs[(size_t)(bb + 16) * D_MODEL + n] = (a1 + bqn) * 0.125f;
  }
}

// ================= 128x256 bf16 MFMA GEMM, triple-buffered (depth-3 prefetch) =================
#define GBM 128
#define GBN 256
#define GBK 32
#define GNT (KD / GBK)   // 32 K-tiles
#define AT  (GBM * GBK)  // 4096 u16 = 8 KB
#define BT  (GBN * GBK)  // 8192 u16 = 16 KB

__device__ __forceinline__ void stageA(const u16* __restrict__ Ag, u16* lbuf,
                                       long m0, int kt, int tid) {
  int c = tid;
  int r = c >> 2, cp = c & 3;
  int scp = cp ^ ((r >> 1) & 3);
  const u16* src = Ag + (m0 + r) * (long)KD + kt * GBK + scp * 8;
  __builtin_amdgcn_global_load_lds((const __attribute__((address_space(1))) void*)src,
      (__attribute__((address_space(3))) void*)(lbuf + (size_t)c * 8), 16, 0, 0);
}

__device__ __forceinline__ void stageB(const u16* __restrict__ Bg, u16* lbuf,
                                       int n0, int kt, int tid) {
  #pragma unroll
  for (int L = 0; L < 2; ++L) {
    int c = tid + L * 512;
    int r = c >> 2, cp = c & 3;
    int scp = cp ^ ((r >> 1) & 3);
    const u16* src = Bg + (size_t)(n0 + r) * KD + kt * GBK + scp * 8;
    __builtin_amdgcn_global_load_lds((const __attribute__((address_space(1))) void*)src,
        (__attribute__((address_space(3))) void*)(lbuf + (size_t)c * 8), 16, 0, 0);
  }
}

__device__ __forceinline__ bf16x8 ldFrag(const u16* buf, int row, int lane) {
  int r  = row + (lane & 15);
  int ch = (lane >> 4) ^ ((r >> 1) & 3);
  return *(const bf16x8*)(buf + (size_t)r * GBK + ch * 8);
}

__global__ __launch_bounds__(512, 4) void gemm_kv(const u16* __restrict__ A,
                                                  const u16* __restrict__ Bm,
                                                  const float* __restrict__ bv,
                                                  float* __restrict__ Kout,
                                                  float* __restrict__ Vout) {
  __shared__ __align__(16) char smem[3 * (GBM + GBN) * GBK * 2];   // 72 KiB
  u16* sAb = (u16*)smem;                 // 3 x 8 KB
  u16* sBb = sAb + 3 * AT;               // 3 x 16 KB

  const int tid  = threadIdx.x;
  const int lane = tid & 63;
  const int wid  = tid >> 6;
  const int wr   = wid >> 2;
  const int wc   = wid & 3;

  int bx = (blockIdx.x & 7) * (gridDim.x >> 3) + (blockIdx.x >> 3);
  const int  mt = bx >> 3;
  const int  nt = bx & 7;
  const long m0 = (long)mt * GBM;
  const int  n0 = nt * GBN;

  // prologue: tiles 0,1,2 (3 loads/thread each, in tile order)
  stageA(A, sAb + 0 * AT, m0, 0, tid);
  stageB(Bm, sBb + 0 * BT, n0, 0, tid);
  stageA(A, sAb + 1 * AT, m0, 1, tid);
  stageB(Bm, sBb + 1 * BT, n0, 1, tid);
  stageA(A, sAb + 2 * AT, m0, 2, tid);
  stageB(Bm, sBb + 2 * BT, n0, 2, tid);

  f32x4 acc[4][4] = {};

  for (int t = 0; t < GNT; ++t) {
    // steady state: tiles t+1, t+2 in flight (6 loads/thread)
    if (t < GNT - 2)       { asm volatile("s_waitcnt vmcnt(6)" ::: "memory"); }
    else if (t == GNT - 2) { asm volatile("s_waitcnt vmcnt(3)" ::: "memory"); }
    else                   { asm volatile("s_waitcnt vmcnt(0)" ::: "memory"); }
    __builtin_amdgcn_s_barrier();

    const int  bi = t % 3;
    const u16* cA = sAb + bi * AT;
    const u16* cB = sBb + bi * BT;
    bf16x8 af[4], bfr[4];
    #pragma unroll
    for (int mf = 0; mf < 4; ++mf) af[mf]  = ldFrag(cA, wr * 64 + mf * 16, lane);
    #pragma unroll
    for (int nf = 0; nf < 4; ++nf) bfr[nf] = ldFrag(cB, wc * 64 + nf * 16, lane);
    asm volatile("s_waitcnt lgkmcnt(0)" ::: "memory");
    __builtin_amdgcn_s_barrier();

    // prefetch tile t+3 into the buffer just consumed
    if (t + 3 < GNT) {
      stageA(A, sAb + bi * AT, m0, t + 3, tid);
      stageB(Bm, sBb + bi * BT, n0, t + 3, tid);
    }

    #pragma unroll
    for (int mf = 0; mf < 4; ++mf)
      #pragma unroll
      for (int nf = 0; nf < 4; ++nf)
        acc[mf][nf] = __builtin_amdgcn_mfma_f32_16x16x32_bf16(af[mf], bfr[nf], acc[mf][nf], 0, 0, 0);
  }

  // ---- coalesced epilogue via LDS transpose ([32][260] f32 slabs) ----
  __syncthreads();
  float (*ep)[260] = (float(*)[260])smem;

  const bool isV = (nt >= 4);
  float* Co = isV ? Vout : Kout;
  const int ncol0 = isV ? (n0 - 1024) : n0;
  float4 bias4[4];
  #pragma unroll
  for (int k = 0; k < 4; ++k) {
    int c4 = (tid + 512 * k) & 63;
    bias4[k] = isV ? reinterpret_cast<const float4*>(bv)[(ncol0 >> 2) + c4]
                   : make_float4(0.f, 0.f, 0.f, 0.f);
  }

  #pragma unroll
  for (int p = 0; p < 4; ++p) {
    if (wr == (p >> 1)) {
      const int mfb = (p & 1) * 2;
      #pragma unroll
      for (int mm = 0; mm < 2; ++mm)
        #pragma unroll
        for (int nf = 0; nf < 4; ++nf)
          #pragma unroll
          for (int r = 0; r < 4; ++r)
            ep[mm * 16 + (lane >> 4) * 4 + r][wc * 64 + nf * 16 + (lane & 15)] =
                acc[mfb + mm][nf][r];
    }
    __syncthreads();
    #pragma unroll
    for (int k = 0; k < 4; ++k) {
      int idx = tid + 512 * k;
      int row = idx >> 6;
      int c4  = idx & 63;
      long grow = m0 + p * 32 + row;
      float4 v = *reinterpret_cast<const float4*>(&ep[row][c4 * 4]);
      v.x += bias4[k].x; v.y += bias4[k].y; v.z += bias4[k].z; v.w += bias4[k].w;
      *reinterpret_cast<float4*>(&Co[grow * D_MODEL + ncol0 + c4 * 4]) = v;
    }
    __syncthreads();
  }
}

// ---------------- attention pass 1: full-row streaming, all 16 heads per block ----------------
__global__ __launch_bounds__(256) void attn_part(const float* __restrict__ qs,
                                                 const float* __restrict__ K,
                                                 const float* __restrict__ V,
                                                 float* __restrict__ part) {
  const int b = blockIdx.x >> 4;
  const int c = blockIdx.x & 15;
  const int tid = threadIdx.x;
  const int h = tid >> 4;
  const int j = tid & 15;
  const int s0 = (c * SEQ) >> 4;
  const int s1 = (((c + 1) * SEQ) >> 4);

  const float4 q4 = ((const float4*)(qs + (size_t)b * D_MODEL))[tid];
  float m = -1e30f, l = 0.f;
  float4 pv = make_float4(0.f, 0.f, 0.f, 0.f);

  int i = s0;
  for (; i + 2 <= s1; i += 2) {
    const float4 kA = ((const float4*)(K + (size_t)(b * SEQ + i) * D_MODEL))[tid];
    const float4 vA = ((const float4*)(V + (size_t)(b * SEQ + i) * D_MODEL))[tid];
    const float4 kB = ((const float4*)(K + (size_t)(b * SEQ + i + 1) * D_MODEL))[tid];
    const float4 vB = ((const float4*)(V + (size_t)(b * SEQ + i + 1) * D_MODEL))[tid];

    float sA = kA.x * q4.x + kA.y * q4.y + kA.z * q4.z + kA.w * q4.w;
    sA += __shfl_xor(sA, 1); sA += __shfl_xor(sA, 2);
    sA += __shfl_xor(sA, 4); sA += __shfl_xor(sA, 8);
    float mn = fmaxf(m, sA);
    float sc = __expf(m - mn);
    float p  = __expf(sA - mn);
    m = mn;
    l = l * sc + p;
    pv.x = pv.x * sc + p * vA.x; pv.y = pv.y * sc + p * vA.y;
    pv.z = pv.z * sc + p * vA.z; pv.w = pv.w * sc + p * vA.w;

    float sB = kB.x * q4.x + kB.y * q4.y + kB.z * q4.z + kB.w * q4.w;
    sB += __shfl_xor(sB, 1); sB += __shfl_xor(sB, 2);
    sB += __shfl_xor(sB, 4); sB += __shfl_xor(sB, 8);
    mn = fmaxf(m, sB);
    sc = __expf(m - mn);
    p  = __expf(sB - mn);
    m = mn;
    l = l * sc + p;
    pv.x = pv.x * sc + p * vB.x; pv.y = pv.y * sc + p * vB.y;
    pv.z = pv.z * sc + p * vB.z; pv.w = pv.w * sc + p * vB.w;
  }
  if (i < s1) {
    const float4 kA = ((const float4*)(K + (size_t)(b * SEQ + i) * D_MODEL))[tid];
    const float4 vA = ((const float4*)(V + (size_t)(b * SEQ + i) * D_MODEL))[tid];
    float sA = kA.x * q4.x + kA.y * q4.y + kA.z * q4.z + kA.w * q4.w;
    sA += __shfl_xor(sA, 1); sA += __shfl_xor(sA, 2);
    sA += __shfl_xor(sA, 4); sA += __shfl_xor(sA, 8);
    float mn = fmaxf(m, sA);
    float sc = __expf(m - mn);
    float p  = __expf(sA - mn);
    m = mn;
    l = l * sc + p;
    pv.x = pv.x * sc + p * vA.x; pv.y = pv.y * sc + p * vA.y;
    pv.z = pv.z * sc + p * vA.z; pv.w = pv.w * sc + p * vA.w;
  }

  float* pp = part + ((size_t)(b * NH + h) * NCH + c) * PSTR;
  *(float4*)(pp + j * 4) = pv;
  if (j == 0) { pp[64] = m; pp[65] = l; }
}

// ---------------- o-projection with fused 16-way chunk-combine: 8 blocks per batch ----------------
__global__ __launch_bounds__(256) void oproj_comb(const float* __restrict__ part,
                                                  const float* __restrict__ Wo,
                                                  const float* __restrict__ bo,
                                                  float* __restrict__ out) {
  const int b = blockIdx.x >> 3, ch = blockIdx.x & 7;
  const int tid = threadIdx.x;
  __shared__ float xs[D_MODEL];

  {
    const int h = tid >> 4;
    const int d = (tid & 15) * 4;
    const float* pp = part + (size_t)(b * NH + h) * NCH * PSTR;
    float M = -1e30f;
    #pragma unroll
    for (int cc = 0; cc < NCH; ++cc) M = fmaxf(M, pp[cc * PSTR + 64]);
    float Lsum = 0.f;
    float4 o = make_float4(0.f, 0.f, 0.f, 0.f);
    #pragma unroll
    for (int cc = 0; cc < NCH; ++cc) {
      const float wgt = __expf(pp[cc * PSTR + 64] - M);
      Lsum += pp[cc * PSTR + 65] * wgt;
      float4 pv = *(const float4*)(pp + cc * PSTR + d);
      o.x += pv.x * wgt; o.y += pv.y * wgt; o.z += pv.z * wgt; o.w += pv.w * wgt;
    }
    const float inv = 1.0f / Lsum;
    xs[h * HD + d]     = o.x * inv;
    xs[h * HD + d + 1] = o.y * inv;
    xs[h * HD + d + 2] = o.z * inv;
    xs[h * HD + d + 3] = o.w * inv;
  }
  __syncthreads();

  const int n = ch * 128 + (tid >> 1);
  const int half = tid & 1;
  const float4* wp = (const float4*)(Wo + (size_t)n * D_MODEL + half * 512);
  const float4* xp = (const float4*)xs + half * 128;
  float a = 0.f;
  #pragma unroll 8
  for (int i = 0; i < 128; ++i) {
    float4 w = wp[i], xv = xp[i];
    a += w.x * xv.x + w.y * xv.y + w.z * xv.z + w.w * xv.w;
  }
  a += __shfl_xor(a, 1);
  if (!half) out[(size_t)b * D_MODEL + n] = a + bo[n];
}

// ---------------- launch ----------------
extern "C" void kernel_launch(void* const* d_in, const int* in_sizes, int n_in,
                              void* d_out, int out_size, void* d_ws, size_t ws_size,
                              hipStream_t stream) {
  const float* hs  = (const float*)d_in[0];
  const float* enc = (const float*)d_in[1];
  const float* Wq  = (const float*)d_in[2];
  const float* bq  = (const float*)d_in[3];
  const float* Wk  = (const float*)d_in[4];
  const float* Wv  = (const float*)d_in[5];
  const float* bv  = (const float*)d_in[6];
  const float* Wo  = (const float*)d_in[7];
  const float* bo  = (const float*)d_in[8];

  float* out   = (float*)d_out;
  float* attnO = out;
  float* Kout  = out + 32768;
  float* Vout  = Kout + (size_t)MROWS * D_MODEL;

  char* ws = (char*)d_ws;
  const size_t off_wkvb = (size_t)MROWS * D_MODEL * 2;        // 98,304,000
  const size_t off_qs   = off_wkvb + 4194304;
  const size_t off_part = off_qs + 131072;                    // 512*16*68*4 = 2,228,224 B

  u16*   encb = (u16*)ws;
  u16*   wkvb = (u16*)(ws + off_wkvb);
  float* qs   = (float*)(ws + off_qs);
  float* part = (float*)(ws + off_part);

  cast_all_q<<<ENC_BLOCKS + W_BLOCKS + QPROJ_BLOCKS, 256, 0, stream>>>(enc, Wk, Wv, hs, Wq, bq,
                                                                       encb, wkvb, qs);

  gemm_kv<<<(MROWS / GBM) * (2048 / GBN), 512, 0, stream>>>(encb, wkvb, bv, Kout, Vout);

  attn_part<<<B_SZ * NCH, 256, 0, stream>>>(qs, Kout, Vout, part);
  oproj_comb<<<B_SZ * 8, 256, 0, stream>>>(part, Wo, bo, attnO);
}